// Round 1
// baseline (579.083 us; speedup 1.0000x reference)
//
#include <hip/hip_runtime.h>
#include <math.h>

// ---- problem constants (match reference) ----
#define N_NODES 50000
#define N_EDGES 800000
#define IN_DIM  128
#define HEADS   4
#define OUT_DIM 16
#define HD      64          // HEADS*OUT_DIM
#define NEG_SLOPE 0.2f

// ---------------------------------------------------------------------------
// float atomic max via int/uint atomics (standard IEEE trick)
// ---------------------------------------------------------------------------
__device__ inline void atomicMaxF(float* addr, float v) {
    if (v >= 0.f) {
        atomicMax((int*)addr, __float_as_int(v));
    } else {
        atomicMin((unsigned int*)addr, __float_as_uint(v));
    }
}

// ---------------------------------------------------------------------------
// K0: init accumulator (d_out region 0), m = -inf, denom = 0
// ---------------------------------------------------------------------------
__global__ void k0_init(float* __restrict__ out_accum,
                        float* __restrict__ m,
                        float* __restrict__ denom) {
    int i = blockIdx.x * blockDim.x + threadIdx.x;
    if (i < N_NODES * HD) out_accum[i] = 0.f;
    if (i < N_NODES * HEADS) {
        m[i] = -INFINITY;
        denom[i] = 0.f;
    }
}

// ---------------------------------------------------------------------------
// K1: node projections  x_l = x@Wl+bl, x_r = x@Wr+br, x_res = x@Wres+bres
// block = 256 threads = 4 nodes x 64 output cols; x rows staged in LDS
// ---------------------------------------------------------------------------
__global__ __launch_bounds__(256)
void k1_proj(const float* __restrict__ x,
             const float* __restrict__ Wl, const float* __restrict__ bl,
             const float* __restrict__ Wr, const float* __restrict__ br,
             const float* __restrict__ Wres, const float* __restrict__ bres,
             float* __restrict__ xl, float* __restrict__ xr,
             float* __restrict__ xres) {
    __shared__ float xs[4][IN_DIM];
    const int base = blockIdx.x * 4;
    for (int i = threadIdx.x; i < 4 * IN_DIM; i += 256) {
        int n = base + (i >> 7);
        xs[i >> 7][i & 127] = (n < N_NODES) ? x[(size_t)n * IN_DIM + (i & 127)] : 0.f;
    }
    __syncthreads();

    const int node = base + (threadIdx.x >> 6);
    const int col  = threadIdx.x & 63;
    if (node >= N_NODES) return;

    float al = bl[col], ar = br[col], ares = bres[col];
    const float* xrow = xs[threadIdx.x >> 6];
#pragma unroll 8
    for (int k = 0; k < IN_DIM; ++k) {
        float xv = xrow[k];
        al   += xv * Wl[k * HD + col];
        ar   += xv * Wr[k * HD + col];
        ares += xv * Wres[k * HD + col];
    }
    xl[(size_t)node * HD + col]   = al;
    xr[(size_t)node * HD + col]   = ar;
    xres[(size_t)node * HD + col] = ares;
}

// ---------------------------------------------------------------------------
// K2: per-edge attention score + segment max.
// 16 threads per edge; thread t handles hd = 4t..4t+3 (float4).
// score[e][h] = sum_d leakyrelu(xl[src]+xr[dst]+ea*We)[h][d] * att[h][d]
// Also emits edge_index (as float) into the output buffer.
// ---------------------------------------------------------------------------
__global__ __launch_bounds__(256)
void k2_score(const int* __restrict__ src, const int* __restrict__ dst,
              const float* __restrict__ ea,
              const float* __restrict__ We, const float* __restrict__ att,
              const float* __restrict__ xl, const float* __restrict__ xr,
              float* __restrict__ score, float* __restrict__ m,
              float* __restrict__ out_ei) {
    const int t = threadIdx.x & 15;            // 0..15 within edge
    const int e = blockIdx.x * 16 + (threadIdx.x >> 4);
    if (e >= N_EDGES) return;

    const int s = src[e];
    const int d = dst[e];
    const float a = ea[e];

    const float4 xlv = *(const float4*)(xl + (size_t)s * HD + t * 4);
    const float4 xrv = *(const float4*)(xr + (size_t)d * HD + t * 4);
    const float4 Wev = *(const float4*)(We + t * 4);
    const float4 atv = *(const float4*)(att + t * 4);

    float f0 = xlv.x + xrv.x + a * Wev.x;
    float f1 = xlv.y + xrv.y + a * Wev.y;
    float f2 = xlv.z + xrv.z + a * Wev.z;
    float f3 = xlv.w + xrv.w + a * Wev.w;
    f0 = f0 > 0.f ? f0 : NEG_SLOPE * f0;
    f1 = f1 > 0.f ? f1 : NEG_SLOPE * f1;
    f2 = f2 > 0.f ? f2 : NEG_SLOPE * f2;
    f3 = f3 > 0.f ? f3 : NEG_SLOPE * f3;

    float p = f0 * atv.x + f1 * atv.y + f2 * atv.z + f3 * atv.w;
    // reduce the 4 threads that share a head (groups of 4 aligned in wave)
    p += __shfl_xor(p, 1);
    p += __shfl_xor(p, 2);

    if ((t & 3) == 0) {
        const int h = t >> 2;
        score[(size_t)e * HEADS + h] = p;
        atomicMaxF(&m[(size_t)d * HEADS + h], p);
    }
    if (t == 0) {
        out_ei[e]           = (float)s;
        out_ei[N_EDGES + e] = (float)d;
    }
}

// ---------------------------------------------------------------------------
// K3: ex = exp(score - m[dst]); denom[dst] += ex  (score overwritten by ex)
// ---------------------------------------------------------------------------
__global__ __launch_bounds__(256)
void k3_exp(const int* __restrict__ dst, const float* __restrict__ m,
            float* __restrict__ score, float* __restrict__ denom) {
    const int i = blockIdx.x * blockDim.x + threadIdx.x;
    if (i >= N_EDGES * HEADS) return;
    const int e = i >> 2;
    const int h = i & 3;
    const int d = dst[e];
    const float ex = expf(score[i] - m[(size_t)d * HEADS + h]);
    score[i] = ex;
    atomicAdd(&denom[(size_t)d * HEADS + h], ex);
}

// ---------------------------------------------------------------------------
// K4: alpha = ex/denom; scatter-add alpha * xl[src] into out accumulator.
// 64 threads per edge (one per hd); 4 edges per 256-thread block.
// Also writes alpha into the output buffer.
// ---------------------------------------------------------------------------
__global__ __launch_bounds__(256)
void k4_agg(const int* __restrict__ src, const int* __restrict__ dst,
            const float* __restrict__ ex, const float* __restrict__ denom,
            const float* __restrict__ xl,
            float* __restrict__ out_accum, float* __restrict__ out_alpha) {
    const int hd = threadIdx.x & 63;
    const int e  = blockIdx.x * 4 + (threadIdx.x >> 6);
    if (e >= N_EDGES) return;

    const int s = src[e];
    const int d = dst[e];
    const int h = hd >> 4;

    const float exv = ex[(size_t)e * HEADS + h];
    const float den = denom[(size_t)d * HEADS + h];
    const float alpha = exv / (den + 1e-16f);

    if ((hd & 15) == 0) out_alpha[(size_t)e * HEADS + h] = alpha;

    const float xv = xl[(size_t)s * HD + hd];
    atomicAdd(&out_accum[(size_t)d * HD + hd], alpha * xv);
}

// ---------------------------------------------------------------------------
// K5: out = elu(accum + bias_out + x_res)   (in place over d_out region 0)
// ---------------------------------------------------------------------------
__global__ __launch_bounds__(256)
void k5_final(float* __restrict__ out, const float* __restrict__ xres,
              const float* __restrict__ bias_out) {
    const int i = blockIdx.x * blockDim.x + threadIdx.x;
    if (i >= N_NODES * HD) return;
    float v = out[i] + xres[i] + bias_out[i & 63];
    out[i] = v > 0.f ? v : (expf(v) - 1.f);
}

// ---------------------------------------------------------------------------
extern "C" void kernel_launch(void* const* d_in, const int* in_sizes, int n_in,
                              void* d_out, int out_size, void* d_ws, size_t ws_size,
                              hipStream_t stream) {
    const float* x        = (const float*)d_in[0];
    const int*   ei       = (const int*)d_in[1];   // [2, E] flat; harness passes ints as int32
    const float* ea       = (const float*)d_in[2];
    const float* Wl       = (const float*)d_in[3];
    const float* bl       = (const float*)d_in[4];
    const float* Wr       = (const float*)d_in[5];
    const float* br       = (const float*)d_in[6];
    const float* We       = (const float*)d_in[7];
    const float* att      = (const float*)d_in[8];
    const float* bias_out = (const float*)d_in[9];
    const float* Wres     = (const float*)d_in[10];
    const float* bres     = (const float*)d_in[11];

    const int* src = ei;
    const int* dst = ei + N_EDGES;

    // output layout (tuple concat, all float32):
    //   [0, N*HD)                     : out
    //   [N*HD, N*HD + 2E)             : edge_index as float
    //   [N*HD + 2E, N*HD + 2E + 4E)   : alpha
    float* out       = (float*)d_out;
    float* out_ei    = out + (size_t)N_NODES * HD;
    float* out_alpha = out_ei + 2 * (size_t)N_EDGES;

    // workspace layout (floats)
    float* ws    = (float*)d_ws;
    float* xl    = ws;                              // N*HD
    float* xr    = xl + (size_t)N_NODES * HD;       // N*HD
    float* xres  = xr + (size_t)N_NODES * HD;       // N*HD
    float* score = xres + (size_t)N_NODES * HD;     // E*H  (becomes ex)
    float* m     = score + (size_t)N_EDGES * HEADS; // N*H
    float* denom = m + (size_t)N_NODES * HEADS;     // N*H

    // K0: init accum / m / denom
    {
        int total = N_NODES * HD;
        k0_init<<<(total + 255) / 256, 256, 0, stream>>>(out, m, denom);
    }
    // K1: projections
    k1_proj<<<(N_NODES + 3) / 4, 256, 0, stream>>>(x, Wl, bl, Wr, br, Wres, bres,
                                                   xl, xr, xres);
    // K2: edge scores + segment max + edge_index output
    k2_score<<<(N_EDGES + 15) / 16, 256, 0, stream>>>(src, dst, ea, We, att,
                                                      xl, xr, score, m, out_ei);
    // K3: exp + denom
    k3_exp<<<(N_EDGES * HEADS + 255) / 256, 256, 0, stream>>>(dst, m, score, denom);
    // K4: alpha + scatter aggregation
    k4_agg<<<(N_EDGES + 3) / 4, 256, 0, stream>>>(src, dst, score, denom, xl,
                                                  out, out_alpha);
    // K5: finalize (bias + residual + ELU)
    k5_final<<<(N_NODES * HD + 255) / 256, 256, 0, stream>>>(out, xres, bias_out);
}

// Round 2
// 436.785 us; speedup vs baseline: 1.3258x; 1.3258x over previous
//
#include <hip/hip_runtime.h>
#include <math.h>

// ---- problem constants (match reference) ----
#define N_NODES 50000
#define N_EDGES 800000
#define IN_DIM  128
#define HEADS   4
#define OUT_DIM 16
#define HD      64          // HEADS*OUT_DIM
#define NEG_SLOPE 0.2f
#define CAP     128         // per-node LDS score cache (deg > CAP -> slow path)

// ---------------------------------------------------------------------------
// K0: zero the per-node edge counters
// ---------------------------------------------------------------------------
__global__ void k0_zero(int* __restrict__ count) {
    int i = blockIdx.x * blockDim.x + threadIdx.x;
    if (i < N_NODES) count[i] = 0;
}

// ---------------------------------------------------------------------------
// K1: node projections  xl = x@Wl+bl, xr = x@Wr+br, xres = x@Wres+bres
// 16 nodes per 256-thread block; thread = (group of 4 nodes) x (col of 64).
// W loads amortized over 4 nodes (register blocking).
// ---------------------------------------------------------------------------
__global__ __launch_bounds__(256)
void k1_proj(const float* __restrict__ x,
             const float* __restrict__ Wl, const float* __restrict__ bl,
             const float* __restrict__ Wr, const float* __restrict__ br,
             const float* __restrict__ Wres, const float* __restrict__ bres,
             float* __restrict__ xl, float* __restrict__ xr,
             float* __restrict__ xres) {
    __shared__ float xs[16][IN_DIM];
    const int base = blockIdx.x * 16;
    // stage 16 node rows (contiguous 2048 floats) into LDS
    {
        const float4* s4 = (const float4*)(x + (size_t)base * IN_DIM);
        float4* d4 = (float4*)&xs[0][0];
        for (int i = threadIdx.x; i < 16 * IN_DIM / 4; i += 256) d4[i] = s4[i];
    }
    __syncthreads();

    const int group = threadIdx.x >> 6;   // 0..3  -> nodes base+group*4 .. +3
    const int col   = threadIdx.x & 63;

    float al0 = 0, al1 = 0, al2 = 0, al3 = 0;
    float ar0 = 0, ar1 = 0, ar2 = 0, ar3 = 0;
    float as0 = 0, as1 = 0, as2 = 0, as3 = 0;
#pragma unroll 4
    for (int k = 0; k < IN_DIM; ++k) {
        const float wl = Wl[k * HD + col];
        const float wr = Wr[k * HD + col];
        const float ws = Wres[k * HD + col];
        const float x0 = xs[group * 4 + 0][k];
        const float x1 = xs[group * 4 + 1][k];
        const float x2 = xs[group * 4 + 2][k];
        const float x3 = xs[group * 4 + 3][k];
        al0 += x0 * wl; al1 += x1 * wl; al2 += x2 * wl; al3 += x3 * wl;
        ar0 += x0 * wr; ar1 += x1 * wr; ar2 += x2 * wr; ar3 += x3 * wr;
        as0 += x0 * ws; as1 += x1 * ws; as2 += x2 * ws; as3 += x3 * ws;
    }
    const float blv = bl[col], brv = br[col], bsv = bres[col];
    const size_t n0 = (size_t)(base + group * 4) * HD + col;
    xl[n0 + 0 * HD] = al0 + blv; xl[n0 + 1 * HD] = al1 + blv;
    xl[n0 + 2 * HD] = al2 + blv; xl[n0 + 3 * HD] = al3 + blv;
    xr[n0 + 0 * HD] = ar0 + brv; xr[n0 + 1 * HD] = ar1 + brv;
    xr[n0 + 2 * HD] = ar2 + brv; xr[n0 + 3 * HD] = ar3 + brv;
    xres[n0 + 0 * HD] = as0 + bsv; xres[n0 + 1 * HD] = as1 + bsv;
    xres[n0 + 2 * HD] = as2 + bsv; xres[n0 + 3 * HD] = as3 + bsv;
}

// ---------------------------------------------------------------------------
// K2: histogram of dst
// ---------------------------------------------------------------------------
__global__ __launch_bounds__(256)
void k2_hist(const int* __restrict__ dst, int* __restrict__ count) {
    int e = blockIdx.x * blockDim.x + threadIdx.x;
    if (e < N_EDGES) atomicAdd(&count[dst[e]], 1);
}

// ---------------------------------------------------------------------------
// K3a/b/c: two-level exclusive scan of count -> rowptr (and cursor copy)
// ---------------------------------------------------------------------------
#define SCAN_BLOCKS 196   // ceil(50000/256)

__global__ __launch_bounds__(256)
void k3a_scan1(const int* __restrict__ count, int* __restrict__ incl,
               int* __restrict__ bsum) {
    __shared__ int s[256];
    const int t = threadIdx.x;
    const int i = blockIdx.x * 256 + t;
    int c = (i < N_NODES) ? count[i] : 0;
    s[t] = c;
    __syncthreads();
    for (int off = 1; off < 256; off <<= 1) {
        int v = (t >= off) ? s[t - off] : 0;
        __syncthreads();
        s[t] += v;
        __syncthreads();
    }
    if (i < N_NODES) incl[i] = s[t];
    if (t == 255) bsum[blockIdx.x] = s[255];
}

__global__ __launch_bounds__(256)
void k3b_scan2(int* __restrict__ bsum, int* __restrict__ boff) {
    __shared__ int s[256];
    const int t = threadIdx.x;
    int c = (t < SCAN_BLOCKS) ? bsum[t] : 0;
    s[t] = c;
    __syncthreads();
    for (int off = 1; off < 256; off <<= 1) {
        int v = (t >= off) ? s[t - off] : 0;
        __syncthreads();
        s[t] += v;
        __syncthreads();
    }
    if (t < SCAN_BLOCKS) boff[t] = s[t] - c;   // exclusive
}

__global__ __launch_bounds__(256)
void k3c_scan3(const int* __restrict__ count, int* __restrict__ incl /*->rowptr*/,
               const int* __restrict__ boff, int* __restrict__ cursor) {
    const int i = blockIdx.x * 256 + threadIdx.x;
    if (i >= N_NODES) return;
    const int v = incl[i] - count[i] + boff[blockIdx.x];  // exclusive prefix
    incl[i] = v;       // rowptr
    cursor[i] = v;
}

// ---------------------------------------------------------------------------
// K4: scatter edge ids into CSR order; also emit edge_index output (float)
// ---------------------------------------------------------------------------
__global__ __launch_bounds__(256)
void k4_scatter(const int* __restrict__ src, const int* __restrict__ dst,
                int* __restrict__ cursor, int* __restrict__ eid,
                float* __restrict__ out_ei) {
    int e = blockIdx.x * blockDim.x + threadIdx.x;
    if (e >= N_EDGES) return;
    const int d = dst[e];
    const int pos = atomicAdd(&cursor[d], 1);
    eid[pos] = e;
    out_ei[e] = (float)src[e];
    out_ei[N_EDGES + e] = (float)d;
}

// ---------------------------------------------------------------------------
// K5: fused per-node GATv2: score + online softmax + aggregation + alpha +
//     bias + residual + ELU.  One 64-lane wave per node; 4 nodes per block.
// ---------------------------------------------------------------------------
__global__ __launch_bounds__(256)
void k5_node(const int* __restrict__ src, const float* __restrict__ ea,
             const int* __restrict__ rowptr, const int* __restrict__ count,
             const int* __restrict__ eid,
             const float* __restrict__ xl, const float* __restrict__ xr,
             const float* __restrict__ xres,
             const float* __restrict__ We, const float* __restrict__ att,
             const float* __restrict__ bias_out,
             float* __restrict__ out, float* __restrict__ out_alpha) {
    __shared__ float sc_lds[4][CAP][HEADS];   // 8 KB

    const int wv   = threadIdx.x >> 6;
    const int lane = threadIdx.x & 63;
    const int n    = blockIdx.x * 4 + wv;     // grid exact: 12500*4 = 50000

    const int base = rowptr[n];
    const int deg  = count[n];

    // per-lane constants (lane == hd index)
    const float xr_l  = xr[(size_t)n * HD + lane];
    const float We_l  = We[lane];
    const float att_l = att[lane];

    float mh = -INFINITY;   // running max for my head (uniform in 16-lane group)
    float dh = 0.f;         // running denom
    float acc = 0.f;        // running sum of exp(sc-m)*xl  (per hd)

    for (int c0 = 0; c0 < deg; c0 += 64) {
        const int nrem = min(64, deg - c0);
        int e_my = 0, s_my = 0;
        float a_my = 0.f;
        if (lane < nrem) {
            e_my = eid[base + c0 + lane];
            s_my = src[e_my];
            a_my = ea[e_my];
        }
        for (int jj = 0; jj < nrem; ++jj) {
            const int   s   = __shfl(s_my, jj);
            const float aev = __shfl(a_my, jj);
            const float xlv = xl[(size_t)s * HD + lane];   // coalesced 256B
            float f = xlv + xr_l + aev * We_l;
            f = f > 0.f ? f : NEG_SLOPE * f;
            float p = f * att_l;
            p += __shfl_xor(p, 1);
            p += __shfl_xor(p, 2);
            p += __shfl_xor(p, 4);
            p += __shfl_xor(p, 8);       // sc for my head, uniform in group
            const float mnew  = fmaxf(mh, p);
            const float scale = expf(mh - mnew);   // 0 when mh=-inf
            const float pe    = expf(p - mnew);
            dh  = dh * scale + pe;
            acc = acc * scale + pe * xlv;
            mh  = mnew;
            const int j = c0 + jj;
            if (j < CAP && (lane & 15) == 0) sc_lds[wv][j][lane >> 4] = p;
        }
    }

    // broadcast all-head m / inv to every lane
    const float inv_my = 1.f / (dh + 1e-16f);
    const float m0 = __shfl(mh, 0),  m1 = __shfl(mh, 16);
    const float m2 = __shfl(mh, 32), m3 = __shfl(mh, 48);
    const float i0 = __shfl(inv_my, 0),  i1 = __shfl(inv_my, 16);
    const float i2 = __shfl(inv_my, 32), i3 = __shfl(inv_my, 48);

    __syncthreads();   // sc_lds visible (uniform: every thread reaches once)

    // alpha write pass (original edge order via e)
    for (int j = lane; j < deg; j += 64) {
        const int e = eid[base + j];
        float s0, s1, s2, s3;
        if (j < CAP) {
            s0 = sc_lds[wv][j][0]; s1 = sc_lds[wv][j][1];
            s2 = sc_lds[wv][j][2]; s3 = sc_lds[wv][j][3];
        } else {
            // slow path (deg > CAP): recompute scores from globals
            const int sN = src[e];
            const float aev = ea[e];
            float sc[4];
            for (int h2 = 0; h2 < 4; ++h2) {
                float a2 = 0.f;
                for (int d2 = 0; d2 < 16; ++d2) {
                    const int hd2 = h2 * 16 + d2;
                    float f = xl[(size_t)sN * HD + hd2] + xr[(size_t)n * HD + hd2]
                              + aev * We[hd2];
                    f = f > 0.f ? f : NEG_SLOPE * f;
                    a2 += f * att[hd2];
                }
                sc[h2] = a2;
            }
            s0 = sc[0]; s1 = sc[1]; s2 = sc[2]; s3 = sc[3];
        }
        float4 a4;
        a4.x = expf(s0 - m0) * i0;
        a4.y = expf(s1 - m1) * i1;
        a4.z = expf(s2 - m2) * i2;
        a4.w = expf(s3 - m3) * i3;
        *(float4*)(out_alpha + (size_t)e * HEADS) = a4;
    }

    // final output: elu(acc/denom + bias + residual)
    float v = acc * inv_my + bias_out[lane] + xres[(size_t)n * HD + lane];
    out[(size_t)n * HD + lane] = v > 0.f ? v : (expf(v) - 1.f);
}

// ---------------------------------------------------------------------------
extern "C" void kernel_launch(void* const* d_in, const int* in_sizes, int n_in,
                              void* d_out, int out_size, void* d_ws, size_t ws_size,
                              hipStream_t stream) {
    const float* x        = (const float*)d_in[0];
    const int*   ei       = (const int*)d_in[1];
    const float* ea       = (const float*)d_in[2];
    const float* Wl       = (const float*)d_in[3];
    const float* bl       = (const float*)d_in[4];
    const float* Wr       = (const float*)d_in[5];
    const float* br       = (const float*)d_in[6];
    const float* We       = (const float*)d_in[7];
    const float* att      = (const float*)d_in[8];
    const float* bias_out = (const float*)d_in[9];
    const float* Wres     = (const float*)d_in[10];
    const float* bres     = (const float*)d_in[11];

    const int* src = ei;
    const int* dst = ei + N_EDGES;

    // output layout (tuple concat, float32): out | edge_index | alpha
    float* out       = (float*)d_out;
    float* out_ei    = out + (size_t)N_NODES * HD;
    float* out_alpha = out_ei + 2 * (size_t)N_EDGES;

    // workspace layout
    float* ws   = (float*)d_ws;
    float* xl   = ws;                               // N*HD
    float* xr   = xl + (size_t)N_NODES * HD;        // N*HD
    float* xres = xr + (size_t)N_NODES * HD;        // N*HD
    int* ibuf   = (int*)(xres + (size_t)N_NODES * HD);
    int* count  = ibuf;                             // N
    int* rowptr = count + N_NODES;                  // N (incl -> excl in place)
    int* cursor = rowptr + N_NODES;                 // N
    int* bsum   = cursor + N_NODES;                 // SCAN_BLOCKS
    int* boff   = bsum + SCAN_BLOCKS;               // SCAN_BLOCKS
    int* eid    = boff + SCAN_BLOCKS;               // E

    k0_zero<<<SCAN_BLOCKS, 256, 0, stream>>>(count);
    k1_proj<<<N_NODES / 16, 256, 0, stream>>>(x, Wl, bl, Wr, br, Wres, bres,
                                              xl, xr, xres);
    k2_hist<<<N_EDGES / 256, 256, 0, stream>>>(dst, count);
    k3a_scan1<<<SCAN_BLOCKS, 256, 0, stream>>>(count, rowptr, bsum);
    k3b_scan2<<<1, 256, 0, stream>>>(bsum, boff);
    k3c_scan3<<<SCAN_BLOCKS, 256, 0, stream>>>(count, rowptr, boff, cursor);
    k4_scatter<<<N_EDGES / 256, 256, 0, stream>>>(src, dst, cursor, eid, out_ei);
    k5_node<<<N_NODES / 4, 256, 0, stream>>>(src, ea, rowptr, count, eid,
                                             xl, xr, xres, We, att, bias_out,
                                             out, out_alpha);
}

// Round 3
// 299.853 us; speedup vs baseline: 1.9312x; 1.4567x over previous
//
#include <hip/hip_runtime.h>
#include <math.h>

// ---- problem constants (match reference) ----
#define N_NODES 50000
#define N_EDGES 800000
#define IN_DIM  128
#define HEADS   4
#define OUT_DIM 16
#define HD      64          // HEADS*OUT_DIM
#define NEG_SLOPE 0.2f
#define CAP     128         // per-node LDS score cache (deg > CAP -> slow path)

// ---------------------------------------------------------------------------
// K0: zero the per-node edge counters
// ---------------------------------------------------------------------------
__global__ void k0_zero(int* __restrict__ count) {
    int i = blockIdx.x * blockDim.x + threadIdx.x;
    if (i < N_NODES) count[i] = 0;
}

// ---------------------------------------------------------------------------
// K1: node projections  xl = x@Wl+bl, xr = x@Wr+br, xres = x@Wres+bres
// 16 nodes per 256-thread block; thread = (group of 4 nodes) x (col of 64).
// ---------------------------------------------------------------------------
__global__ __launch_bounds__(256)
void k1_proj(const float* __restrict__ x,
             const float* __restrict__ Wl, const float* __restrict__ bl,
             const float* __restrict__ Wr, const float* __restrict__ br,
             const float* __restrict__ Wres, const float* __restrict__ bres,
             float* __restrict__ xl, float* __restrict__ xr,
             float* __restrict__ xres) {
    __shared__ float xs[16][IN_DIM];
    const int base = blockIdx.x * 16;
    {
        const float4* s4 = (const float4*)(x + (size_t)base * IN_DIM);
        float4* d4 = (float4*)&xs[0][0];
        for (int i = threadIdx.x; i < 16 * IN_DIM / 4; i += 256) d4[i] = s4[i];
    }
    __syncthreads();

    const int group = threadIdx.x >> 6;   // 0..3  -> nodes base+group*4 .. +3
    const int col   = threadIdx.x & 63;

    float al0 = 0, al1 = 0, al2 = 0, al3 = 0;
    float ar0 = 0, ar1 = 0, ar2 = 0, ar3 = 0;
    float as0 = 0, as1 = 0, as2 = 0, as3 = 0;
#pragma unroll 4
    for (int k = 0; k < IN_DIM; ++k) {
        const float wl = Wl[k * HD + col];
        const float wr = Wr[k * HD + col];
        const float ws = Wres[k * HD + col];
        const float x0 = xs[group * 4 + 0][k];
        const float x1 = xs[group * 4 + 1][k];
        const float x2 = xs[group * 4 + 2][k];
        const float x3 = xs[group * 4 + 3][k];
        al0 += x0 * wl; al1 += x1 * wl; al2 += x2 * wl; al3 += x3 * wl;
        ar0 += x0 * wr; ar1 += x1 * wr; ar2 += x2 * wr; ar3 += x3 * wr;
        as0 += x0 * ws; as1 += x1 * ws; as2 += x2 * ws; as3 += x3 * ws;
    }
    const float blv = bl[col], brv = br[col], bsv = bres[col];
    const size_t n0 = (size_t)(base + group * 4) * HD + col;
    xl[n0 + 0 * HD] = al0 + blv; xl[n0 + 1 * HD] = al1 + blv;
    xl[n0 + 2 * HD] = al2 + blv; xl[n0 + 3 * HD] = al3 + blv;
    xr[n0 + 0 * HD] = ar0 + brv; xr[n0 + 1 * HD] = ar1 + brv;
    xr[n0 + 2 * HD] = ar2 + brv; xr[n0 + 3 * HD] = ar3 + brv;
    xres[n0 + 0 * HD] = as0 + bsv; xres[n0 + 1 * HD] = as1 + bsv;
    xres[n0 + 2 * HD] = as2 + bsv; xres[n0 + 3 * HD] = as3 + bsv;
}

// ---------------------------------------------------------------------------
// K2: histogram of dst
// ---------------------------------------------------------------------------
__global__ __launch_bounds__(256)
void k2_hist(const int* __restrict__ dst, int* __restrict__ count) {
    int e = blockIdx.x * blockDim.x + threadIdx.x;
    if (e < N_EDGES) atomicAdd(&count[dst[e]], 1);
}

// ---------------------------------------------------------------------------
// K3a/b/c: two-level exclusive scan of count -> rowptr (and cursor copy)
// ---------------------------------------------------------------------------
#define SCAN_BLOCKS 196   // ceil(50000/256)

__global__ __launch_bounds__(256)
void k3a_scan1(const int* __restrict__ count, int* __restrict__ incl,
               int* __restrict__ bsum) {
    __shared__ int s[256];
    const int t = threadIdx.x;
    const int i = blockIdx.x * 256 + t;
    int c = (i < N_NODES) ? count[i] : 0;
    s[t] = c;
    __syncthreads();
    for (int off = 1; off < 256; off <<= 1) {
        int v = (t >= off) ? s[t - off] : 0;
        __syncthreads();
        s[t] += v;
        __syncthreads();
    }
    if (i < N_NODES) incl[i] = s[t];
    if (t == 255) bsum[blockIdx.x] = s[255];
}

__global__ __launch_bounds__(256)
void k3b_scan2(int* __restrict__ bsum, int* __restrict__ boff) {
    __shared__ int s[256];
    const int t = threadIdx.x;
    int c = (t < SCAN_BLOCKS) ? bsum[t] : 0;
    s[t] = c;
    __syncthreads();
    for (int off = 1; off < 256; off <<= 1) {
        int v = (t >= off) ? s[t - off] : 0;
        __syncthreads();
        s[t] += v;
        __syncthreads();
    }
    if (t < SCAN_BLOCKS) boff[t] = s[t] - c;   // exclusive
}

__global__ __launch_bounds__(256)
void k3c_scan3(const int* __restrict__ count, int* __restrict__ incl /*->rowptr*/,
               const int* __restrict__ boff, int* __restrict__ cursor) {
    const int i = blockIdx.x * 256 + threadIdx.x;
    if (i >= N_NODES) return;
    const int v = incl[i] - count[i] + boff[blockIdx.x];  // exclusive prefix
    incl[i] = v;       // rowptr
    cursor[i] = v;
}

// ---------------------------------------------------------------------------
// K4: scatter edges into CSR order (eid + pre-gathered src/ea);
//     also emit edge_index output (float)
// ---------------------------------------------------------------------------
__global__ __launch_bounds__(256)
void k4_scatter(const int* __restrict__ src, const int* __restrict__ dst,
                const float* __restrict__ ea,
                int* __restrict__ cursor, int* __restrict__ eid,
                int* __restrict__ src_s, float* __restrict__ ea_s,
                float* __restrict__ out_ei) {
    int e = blockIdx.x * blockDim.x + threadIdx.x;
    if (e >= N_EDGES) return;
    const int d = dst[e];
    const int s = src[e];
    const int pos = atomicAdd(&cursor[d], 1);
    eid[pos] = e;
    src_s[pos] = s;
    ea_s[pos] = ea[e];
    out_ei[e] = (float)s;
    out_ei[N_EDGES + e] = (float)d;
}

// ---------------------------------------------------------------------------
// K5: fused per-node GATv2. One wave per node, but 4 edges IN FLIGHT:
//     4 groups x 16 lanes; lane u of a group owns hd = 4u..4u+3 (float4).
//     Each group runs its own online softmax over its (deg/4) edges with
//     next-chunk xl prefetch; groups flash-merge at the end via shfl_xor.
// ---------------------------------------------------------------------------
__global__ __launch_bounds__(256)
void k5_node(const int* __restrict__ src_s, const float* __restrict__ ea_s,
             const int* __restrict__ rowptr, const int* __restrict__ count,
             const int* __restrict__ eid,
             const float* __restrict__ xl, const float* __restrict__ xr,
             const float* __restrict__ xres,
             const float* __restrict__ We, const float* __restrict__ att,
             const float* __restrict__ bias_out,
             float* __restrict__ out, float* __restrict__ out_alpha) {
    __shared__ float sc_lds[4][CAP][HEADS];   // 8 KB

    const int wv   = threadIdx.x >> 6;
    const int lane = threadIdx.x & 63;
    const int u    = lane & 15;           // position in group (hd = 4u..4u+3)
    const int g    = lane >> 4;           // edge group 0..3
    const int n    = blockIdx.x * 4 + wv; // grid exact: 12500*4 = 50000

    const int base = rowptr[n];
    const int deg  = count[n];

    const float4 xr4 = *(const float4*)(xr  + (size_t)n * HD + 4 * u);
    const float4 We4 = *(const float4*)(We  + 4 * u);
    const float4 at4 = *(const float4*)(att + 4 * u);

    float m = -INFINITY, dsum = 0.f;
    float4 acc = make_float4(0.f, 0.f, 0.f, 0.f);

    for (int c0 = 0; c0 < deg; c0 += 64) {
        const int nrem = min(64, deg - c0);
        int s_my = 0; float a_my = 0.f;
        if (lane < nrem) {
            s_my = src_s[base + c0 + lane];   // contiguous (pre-sorted)
            a_my = ea_s[base + c0 + lane];
        }
        const int nchunk = (nrem + 3) >> 2;

        // prefetch chunk 0 for this group
        int   j   = g;
        bool  v   = j < nrem;
        int   s   = __shfl(s_my, j);
        float aev = __shfl(a_my, j);
        float4 xlv = make_float4(0.f, 0.f, 0.f, 0.f);
        if (v) xlv = *(const float4*)(xl + (size_t)s * HD + 4 * u);

        for (int c = 0; c < nchunk; ++c) {
            const float4 cur  = xlv;
            const bool   curv = v;
            const float  ca   = aev;
            const int    cj   = 4 * c + g;
            // prefetch next chunk
            j = 4 * (c + 1) + g;
            v = j < nrem;
            s   = __shfl(s_my, j & 63);
            aev = __shfl(a_my, j & 63);
            if (v) xlv = *(const float4*)(xl + (size_t)s * HD + 4 * u);

            if (curv) {
                float f0 = cur.x + xr4.x + ca * We4.x;
                float f1 = cur.y + xr4.y + ca * We4.y;
                float f2 = cur.z + xr4.z + ca * We4.z;
                float f3 = cur.w + xr4.w + ca * We4.w;
                f0 = f0 > 0.f ? f0 : NEG_SLOPE * f0;
                f1 = f1 > 0.f ? f1 : NEG_SLOPE * f1;
                f2 = f2 > 0.f ? f2 : NEG_SLOPE * f2;
                f3 = f3 > 0.f ? f3 : NEG_SLOPE * f3;
                float p = f0 * at4.x + f1 * at4.y + f2 * at4.z + f3 * at4.w;
                p += __shfl_xor(p, 1);
                p += __shfl_xor(p, 2);     // per-head score, uniform in 4-lane subgroup
                const int jj = c0 + cj;
                if (jj < CAP && (u & 3) == 0) sc_lds[wv][jj][u >> 2] = p;
                const float mnew = fmaxf(m, p);
                const float scl  = __expf(m - mnew);   // m=-inf -> 0
                const float pe   = __expf(p - mnew);
                dsum  = dsum * scl + pe;
                acc.x = acc.x * scl + pe * cur.x;
                acc.y = acc.y * scl + pe * cur.y;
                acc.z = acc.z * scl + pe * cur.z;
                acc.w = acc.w * scl + pe * cur.w;
                m = mnew;
            }
        }
    }

    // flash-merge the 4 groups (lanes u, u+16, u+32, u+48 share an hd slice)
#pragma unroll
    for (int off = 16; off <= 32; off <<= 1) {
        const float mo = __shfl_xor(m, off);
        const float d2 = __shfl_xor(dsum, off);
        float4 a2;
        a2.x = __shfl_xor(acc.x, off);
        a2.y = __shfl_xor(acc.y, off);
        a2.z = __shfl_xor(acc.z, off);
        a2.w = __shfl_xor(acc.w, off);
        const float mm = fmaxf(m, mo);
        const float s1 = (m  == -INFINITY) ? 0.f : __expf(m - mm);
        const float s2 = (mo == -INFINITY) ? 0.f : __expf(mo - mm);
        dsum  = dsum * s1 + d2 * s2;
        acc.x = acc.x * s1 + a2.x * s2;
        acc.y = acc.y * s1 + a2.y * s2;
        acc.z = acc.z * s1 + a2.z * s2;
        acc.w = acc.w * s1 + a2.w * s2;
        m = mm;
    }
    const float inv = 1.f / (dsum + 1e-16f);

    // broadcast per-head m / inv (head h lives at lane 4h)
    const float m0 = __shfl(m, 0),  m1 = __shfl(m, 4);
    const float m2 = __shfl(m, 8),  m3 = __shfl(m, 12);
    const float i0 = __shfl(inv, 0), i1 = __shfl(inv, 4);
    const float i2 = __shfl(inv, 8), i3 = __shfl(inv, 12);

    __syncthreads();   // sc_lds visibility (uniform; each wave touches own slice)

    // alpha write pass (original edge order via eid)
    for (int jj = lane; jj < deg; jj += 64) {
        const int e = eid[base + jj];
        float s0, s1, s2, s3;
        if (jj < CAP) {
            s0 = sc_lds[wv][jj][0]; s1 = sc_lds[wv][jj][1];
            s2 = sc_lds[wv][jj][2]; s3 = sc_lds[wv][jj][3];
        } else {
            // slow path (deg > CAP): recompute from globals
            const int   sN  = src_s[base + jj];
            const float aev = ea_s[base + jj];
            float sc[4];
            for (int h2 = 0; h2 < 4; ++h2) {
                float a2 = 0.f;
                for (int d2 = 0; d2 < 16; ++d2) {
                    const int hd2 = h2 * 16 + d2;
                    float f = xl[(size_t)sN * HD + hd2] + xr[(size_t)n * HD + hd2]
                              + aev * We[hd2];
                    f = f > 0.f ? f : NEG_SLOPE * f;
                    a2 += f * att[hd2];
                }
                sc[h2] = a2;
            }
            s0 = sc[0]; s1 = sc[1]; s2 = sc[2]; s3 = sc[3];
        }
        float4 a4;
        a4.x = __expf(s0 - m0) * i0;
        a4.y = __expf(s1 - m1) * i1;
        a4.z = __expf(s2 - m2) * i2;
        a4.w = __expf(s3 - m3) * i3;
        *(float4*)(out_alpha + (size_t)e * HEADS) = a4;
    }

    // final output (merged acc identical in all groups; group 0 writes)
    if (g == 0) {
        const float4 xs4 = *(const float4*)(xres + (size_t)n * HD + 4 * u);
        const float4 b4  = *(const float4*)(bias_out + 4 * u);
        float4 o;
        o.x = acc.x * inv + b4.x + xs4.x;
        o.y = acc.y * inv + b4.y + xs4.y;
        o.z = acc.z * inv + b4.z + xs4.z;
        o.w = acc.w * inv + b4.w + xs4.w;
        o.x = o.x > 0.f ? o.x : __expf(o.x) - 1.f;
        o.y = o.y > 0.f ? o.y : __expf(o.y) - 1.f;
        o.z = o.z > 0.f ? o.z : __expf(o.z) - 1.f;
        o.w = o.w > 0.f ? o.w : __expf(o.w) - 1.f;
        *(float4*)(out + (size_t)n * HD + 4 * u) = o;
    }
}

// ---------------------------------------------------------------------------
extern "C" void kernel_launch(void* const* d_in, const int* in_sizes, int n_in,
                              void* d_out, int out_size, void* d_ws, size_t ws_size,
                              hipStream_t stream) {
    const float* x        = (const float*)d_in[0];
    const int*   ei       = (const int*)d_in[1];
    const float* ea       = (const float*)d_in[2];
    const float* Wl       = (const float*)d_in[3];
    const float* bl       = (const float*)d_in[4];
    const float* Wr       = (const float*)d_in[5];
    const float* br       = (const float*)d_in[6];
    const float* We       = (const float*)d_in[7];
    const float* att      = (const float*)d_in[8];
    const float* bias_out = (const float*)d_in[9];
    const float* Wres     = (const float*)d_in[10];
    const float* bres     = (const float*)d_in[11];

    const int* src = ei;
    const int* dst = ei + N_EDGES;

    // output layout (tuple concat, float32): out | edge_index | alpha
    float* out       = (float*)d_out;
    float* out_ei    = out + (size_t)N_NODES * HD;
    float* out_alpha = out_ei + 2 * (size_t)N_EDGES;

    // workspace layout
    float* ws   = (float*)d_ws;
    float* xl   = ws;                               // N*HD
    float* xr   = xl + (size_t)N_NODES * HD;        // N*HD
    float* xres = xr + (size_t)N_NODES * HD;        // N*HD
    float* ea_s = xres + (size_t)N_NODES * HD;      // E
    int* ibuf   = (int*)(ea_s + N_EDGES);
    int* count  = ibuf;                             // N
    int* rowptr = count + N_NODES;                  // N
    int* cursor = rowptr + N_NODES;                 // N
    int* bsum   = cursor + N_NODES;                 // SCAN_BLOCKS
    int* boff   = bsum + SCAN_BLOCKS;               // SCAN_BLOCKS
    int* eid    = boff + SCAN_BLOCKS;               // E
    int* src_s  = eid + N_EDGES;                    // E

    k0_zero<<<SCAN_BLOCKS, 256, 0, stream>>>(count);
    k1_proj<<<N_NODES / 16, 256, 0, stream>>>(x, Wl, bl, Wr, br, Wres, bres,
                                              xl, xr, xres);
    k2_hist<<<N_EDGES / 256, 256, 0, stream>>>(dst, count);
    k3a_scan1<<<SCAN_BLOCKS, 256, 0, stream>>>(count, rowptr, bsum);
    k3b_scan2<<<1, 256, 0, stream>>>(bsum, boff);
    k3c_scan3<<<SCAN_BLOCKS, 256, 0, stream>>>(count, rowptr, boff, cursor);
    k4_scatter<<<N_EDGES / 256, 256, 0, stream>>>(src, dst, ea, cursor, eid,
                                                  src_s, ea_s, out_ei);
    k5_node<<<N_NODES / 4, 256, 0, stream>>>(src_s, ea_s, rowptr, count, eid,
                                             xl, xr, xres, We, att, bias_out,
                                             out, out_alpha);
}